// Round 14
// baseline (394.181 us; speedup 1.0000x reference)
//
#include <hip/hip_runtime.h>
#include <math.h>

// ---------------- problem constants (fixed by setup_inputs) ----------------
constexpr int Md   = 2048;      // m
constexpr int NDIM = 784;       // x feature dim
constexpr int DYC  = 10;        // y feature dim
constexpr int MM   = Md * Md;   // 4,194,304
// weighted median: per unordered pair i<j weight 4; diagonal weight 1.
// Dx/Dy: FULL matrix weight 2 (mirror bitwise equal) minus 1 per diag elem.
// Components: TRIANGLE weight 4 minus 3m at key(0.0) (diag exactly 0).
// Total each = 2m^2 - m = 8,386,560 (even).
constexpr unsigned RANK_LO = 4193279u;
constexpr unsigned RANK_HI = 4193280u;
constexpr int NPROB = 12;       // Dx, Dy, 10 components
constexpr int NB    = 256;      // blocks per problem
// Radix split 12/12/8 (R12 post-mortem: 13-bit lh = 40KB LDS capped occupancy
// at 4 blocks/CU on a latency-bound scan; 12-bit lh = 24KB -> 6 blocks/CU).
constexpr int NBINS = 4096;

// ---------------- workspace layout (bytes) ----------------
constexpr size_t OFF_DX     = 0;                          // float[MM]  16 MB
constexpr size_t OFF_DY     = OFF_DX + (size_t)MM * 4;    // float[MM]  16 MB
constexpr size_t OFF_RX     = OFF_DY + (size_t)MM * 4;    // double[2048]
constexpr size_t OFF_RY     = OFF_RX + Md * 8;            // double[2048]
constexpr size_t OFF_RC     = OFF_RY + Md * 8;            // double[10*2048]
constexpr size_t OFF_GACC   = OFF_RC + (size_t)DYC * Md * 8;   // double[64]
constexpr size_t OFF_HISTA  = OFF_GACC + 64 * 8;          // uint32[12*4096]
constexpr size_t OFF_HISTB  = OFF_HISTA + (size_t)NPROB * NBINS * 4;
constexpr size_t OFF_RES    = OFF_HISTB + (size_t)NPROB * NBINS * 4; // double[72]
constexpr size_t OFF_JOBS   = OFF_RES + 72 * 8;           // uint32[12*5]
constexpr size_t OFF_Q      = OFF_JOBS + NPROB * 5 * 4;   // float[12]: 2*sigma^2
constexpr size_t OFF_RXN    = OFF_Q + NPROB * 4;          // float[2048]
constexpr size_t OFF_YT     = OFF_RXN + Md * 4;           // float[10*2048]
constexpr size_t WS_NEED    = OFF_YT + (size_t)DYC * Md * 4;
constexpr size_t ZERO_BASE  = OFF_GACC;
constexpr size_t ZERO_LEN   = OFF_JOBS - OFF_GACC;        // gacc+histA+histB+res
constexpr int NTRI  = 528;      // 32*33/2 lower-triangle 64x64 block pairs

// ---------------- helpers ----------------
typedef _Float16 f16x8 __attribute__((ext_vector_type(8)));
typedef _Float16 f16x4 __attribute__((ext_vector_type(4)));
typedef float    f32x16 __attribute__((ext_vector_type(16)));

__device__ __forceinline__ unsigned fkey(float v) {
  unsigned u = __float_as_uint(v);
  return (u & 0x80000000u) ? ~u : (u | 0x80000000u);
}
__device__ __forceinline__ float keyinv(unsigned k) {
  unsigned u = (k & 0x80000000u) ? (k ^ 0x80000000u) : ~k;
  return __uint_as_float(u);
}
__device__ __forceinline__ f16x8 ld8(const _Float16* p) {
  f16x4 lo = *(const f16x4*)p;
  f16x4 hi = *(const f16x4*)(p + 4);
  f16x8 r;
  r[0]=lo[0]; r[1]=lo[1]; r[2]=lo[2]; r[3]=lo[3];
  r[4]=hi[0]; r[5]=hi[1]; r[6]=hi[2]; r[7]=hi[3];
  return r;
}
__device__ __forceinline__ double waveReduceD(double v) {
  #pragma unroll
  for (int o = 32; o > 0; o >>= 1) v += __shfl_down(v, o, 64);
  return v;
}
__device__ __forceinline__ double blockReduceD(double v) {
  __shared__ double sred[4];
  v = waveReduceD(v);
  int lane = threadIdx.x & 63;
  int w    = threadIdx.x >> 6;
  __syncthreads();
  if (lane == 0) sred[w] = v;
  __syncthreads();
  double r = 0.0;
  if (threadIdx.x == 0) { r = sred[0] + sred[1] + sred[2] + sred[3]; }
  return r;
}

// ---------------- kernels ----------------
__global__ void fail_kernel(float* out) { if (threadIdx.x == 0) out[0] = 0.0f; }

// prep: rownorm (blocks 0..2047) + Y transpose (2048..2127) + jobs init (2128)
__global__ __launch_bounds__(256) void prep_kernel(const float* __restrict__ X,
                                                   const float* __restrict__ Y,
                                                   float* __restrict__ rxn,
                                                   float* __restrict__ Yt,
                                                   unsigned* __restrict__ jobs) {
  int bb = blockIdx.x;
  if (bb < Md) {
    double acc = 0.0;
    for (int k = threadIdx.x; k < NDIM; k += 256) {
      float v = X[bb * NDIM + k];
      acc += (double)v * (double)v;
    }
    double r = blockReduceD(acc);
    if (threadIdx.x == 0) rxn[bb] = (float)r;
  } else if (bb < Md + 80) {
    int e = (bb - Md) * 256 + threadIdx.x;
    if (e < Md * DYC) {
      int i = e / DYC, c = e % DYC;
      Yt[c * Md + i] = Y[e];
    }
  } else {
    int t = threadIdx.x;
    if (t < NPROB * 5) {
      int w = t % 5;
      jobs[t] = (w == 1) ? RANK_LO : (w == 3) ? RANK_HI : 0u;
    }
  }
}

// merged distance kernel over LOWER-TRIANGLE block pairs only (D symmetric;
// mirror-write both tiles — same value bitwise, fp add commutes).
// z=0: Dx via fp16 hi/lo split MFMA; z=1: Dy direct.
__global__ __launch_bounds__(256) void dist_kernel(const float* __restrict__ X,
                                                   const float* __restrict__ Y,
                                                   const float* __restrict__ rxn,
                                                   float* __restrict__ Dx,
                                                   float* __restrict__ Dy) {
  __shared__ _Float16 Ah[64][68], Al[64][68], Bh[64][68], Bl[64][68];
  __shared__ float Yi[64][10], Yj[64][10];
  const int tid = threadIdx.x;
  // map linear triangle index -> (bi, bj), bi >= bj
  int t0 = blockIdx.x;
  int bi = (int)((sqrtf(8.0f * (float)t0 + 1.0f) - 1.0f) * 0.5f);
  while ((bi + 1) * (bi + 2) / 2 <= t0) ++bi;
  while (bi * (bi + 1) / 2 > t0) --bi;
  int bj = t0 - bi * (bi + 1) / 2;
  const int i0 = bi * 64, j0 = bj * 64;
  const bool offdiag = (bi != bj);

  if (blockIdx.z == 1) {
    // ---- Dy[i,j] = sum_c (y_ic - y_jc)^2 ----
    for (int t = tid; t < 640; t += 256) {
      int r = t / 10, c = t % 10;
      Yi[r][c] = Y[(i0 + r) * DYC + c];
      Yj[r][c] = Y[(j0 + r) * DYC + c];
    }
    __syncthreads();
    int jj = tid & 63;
    int ii0 = (tid >> 6) * 16;
    float yj[10];
    #pragma unroll
    for (int c = 0; c < 10; ++c) yj[c] = Yj[jj][c];
    for (int r = 0; r < 16; ++r) {
      int ii = ii0 + r;
      float s = 0.f;
      #pragma unroll
      for (int c = 0; c < 10; ++c) { float d = Yi[ii][c] - yj[c]; s = fmaf(d, d, s); }
      Dy[(size_t)(i0 + ii) * Md + (j0 + jj)] = s;
      if (offdiag) Dy[(size_t)(j0 + jj) * Md + (i0 + ii)] = s;
    }
    return;
  }

  // ---- Dx = rx[i] + rx[j] - 2*(hh + (c1+c2)), fp16 hi/lo split MFMA ----
  const int wave = tid >> 6, lane = tid & 63;
  const int wr = (wave >> 1) * 32, wc = (wave & 1) * 32;
  const int srow = tid >> 2;
  const int sseg = (tid & 3) * 8;

  f32x16 acc_hh = {}, acc_c1 = {}, acc_c2 = {};

  const float* Arow = X + (size_t)(i0 + srow) * NDIM;
  const float* Brow = X + (size_t)(j0 + srow) * NDIM;
  const int lrow = lane & 31;
  const int lko  = (lane >> 5) * 8;

  for (int k0 = 0; k0 < 800; k0 += 32) {
    float a[8], b[8];
    if (k0 + 32 <= NDIM) {
      float4 a4 = *(const float4*)(Arow + k0 + sseg);
      float4 a5 = *(const float4*)(Arow + k0 + sseg + 4);
      float4 b4 = *(const float4*)(Brow + k0 + sseg);
      float4 b5 = *(const float4*)(Brow + k0 + sseg + 4);
      a[0]=a4.x; a[1]=a4.y; a[2]=a4.z; a[3]=a4.w; a[4]=a5.x; a[5]=a5.y; a[6]=a5.z; a[7]=a5.w;
      b[0]=b4.x; b[1]=b4.y; b[2]=b4.z; b[3]=b4.w; b[4]=b5.x; b[5]=b5.y; b[6]=b5.z; b[7]=b5.w;
    } else {
      #pragma unroll
      for (int u = 0; u < 8; ++u) {
        int k = k0 + sseg + u;
        a[u] = (k < NDIM) ? Arow[k] : 0.0f;
        b[u] = (k < NDIM) ? Brow[k] : 0.0f;
      }
    }
    __syncthreads();
    #pragma unroll
    for (int half = 0; half < 2; ++half) {
      f16x4 vah, val_, vbh, vbl;
      #pragma unroll
      for (int u = 0; u < 4; ++u) {
        float av = a[half * 4 + u];
        _Float16 h = (_Float16)av;
        vah[u] = h; val_[u] = (_Float16)(av - (float)h);
        float bv = b[half * 4 + u];
        _Float16 g = (_Float16)bv;
        vbh[u] = g; vbl[u] = (_Float16)(bv - (float)g);
      }
      *(f16x4*)&Ah[srow][sseg + half * 4] = vah;
      *(f16x4*)&Al[srow][sseg + half * 4] = val_;
      *(f16x4*)&Bh[srow][sseg + half * 4] = vbh;
      *(f16x4*)&Bl[srow][sseg + half * 4] = vbl;
    }
    __syncthreads();
    #pragma unroll
    for (int ks = 0; ks < 2; ++ks) {
      int ko = ks * 16 + lko;
      f16x8 fah = ld8(&Ah[wr + lrow][ko]);
      f16x8 fal = ld8(&Al[wr + lrow][ko]);
      f16x8 fbh = ld8(&Bh[wc + lrow][ko]);
      f16x8 fbl = ld8(&Bl[wc + lrow][ko]);
      acc_hh = __builtin_amdgcn_mfma_f32_32x32x16_f16(fah, fbh, acc_hh, 0, 0, 0);
      acc_c1 = __builtin_amdgcn_mfma_f32_32x32x16_f16(fah, fbl, acc_c1, 0, 0, 0);
      acc_c2 = __builtin_amdgcn_mfma_f32_32x32x16_f16(fal, fbh, acc_c2, 0, 0, 0);
    }
  }
  int col = j0 + wc + (lane & 31);
  float rj = rxn[col];
  #pragma unroll
  for (int r = 0; r < 16; ++r) {
    int row = i0 + wr + (r & 3) + 8 * (r >> 2) + 4 * (lane >> 5);
    float t = rxn[row] + rj;
    float cc = acc_c1[r] + acc_c2[r];
    float v = fmaf(-2.0f, cc, fmaf(-2.0f, acc_hh[r], t));
    Dx[(size_t)row * Md + col] = v;
    if (offdiag) Dx[(size_t)col * Md + row] = v;   // mirror (bitwise-equal value)
  }
}

// radix-select histogram, split 12/12/8. Dx/Dy (probs 0,1): FULL-matrix flat
// float4 scan, weight 2, minus diag (Dx: per-elem -1 rescan; Dy: -m at
// key(0)). Components (probs 2-11, LDS-computed): TRIANGLE with paired rows
// (ra, 2047-ra) -> uniform 2049 elems/pair, weight 4, minus 3m at key(0.0).
// 24KB LDS -> 6 blocks/CU (the scan is latency-bound; occupancy is the fix).
// grid (NB, 12). Levels: 12 bits [31:20], 12 bits [19:8], 8 bits [7:0].
__global__ __launch_bounds__(256) void hist_kernel(const float* __restrict__ Dx,
                                                   const float* __restrict__ Dy,
                                                   const float* __restrict__ Yt,
                                                   unsigned* __restrict__ histA,
                                                   unsigned* __restrict__ histB,
                                                   const unsigned* __restrict__ jobs,
                                                   int level) {
  __shared__ unsigned lh[NBINS];   // 16 KB
  __shared__ float ycol[Md];       // 8 KB
  int prob = blockIdx.y;
  int nbins = (level == 2) ? 256 : NBINS;
  for (int b = threadIdx.x; b < nbins; b += 256) lh[b] = 0;
  const float* Mptr = (prob == 0) ? Dx : (prob == 1 ? Dy : nullptr);
  if (prob >= 2) {
    const float* src = Yt + (size_t)(prob - 2) * Md;
    for (int i = threadIdx.x; i < Md; i += 256) ycol[i] = src[i];
  }
  __syncthreads();
  unsigned pfxL = jobs[prob * 5 + 0];
  unsigned pfxH = jobs[prob * 5 + 2];
  unsigned div  = jobs[prob * 5 + 4];
  unsigned* ghB = histB + prob * NBINS;

  auto histo = [&](float v, unsigned w) {
    unsigned key = fkey(v);
    if (level == 0) {
      atomicAdd(&lh[key >> 20], w);
    } else if (level == 1) {
      if ((key >> 20) == pfxL)             atomicAdd(&lh[(key >> 8) & 4095u], w);
      else if (div && (key >> 20) == pfxH) atomicAdd(&ghB[(key >> 8) & 4095u], w);
    } else {
      if ((key >> 8) == pfxL)              atomicAdd(&lh[key & 255u], w);
      else if (div && (key >> 8) == pfxH)  atomicAdd(&ghB[key & 255u], w);
    }
  };

  if (Mptr) {
    // flat chunk: 16384 elements = 4096 float4 per block
    const float4* M4 = (const float4*)Mptr + (size_t)blockIdx.x * 4096;
    #pragma unroll 1
    for (int it = 0; it < 16; it += 4) {
      float4 v0 = M4[(it + 0) * 256 + threadIdx.x];
      float4 v1 = M4[(it + 1) * 256 + threadIdx.x];
      float4 v2 = M4[(it + 2) * 256 + threadIdx.x];
      float4 v3 = M4[(it + 3) * 256 + threadIdx.x];
      histo(v0.x, 2u); histo(v0.y, 2u); histo(v0.z, 2u); histo(v0.w, 2u);
      histo(v1.x, 2u); histo(v1.y, 2u); histo(v1.z, 2u); histo(v1.w, 2u);
      histo(v2.x, 2u); histo(v2.y, 2u); histo(v2.z, 2u); histo(v2.w, 2u);
      histo(v3.x, 2u); histo(v3.y, 2u); histo(v3.z, 2u); histo(v3.w, 2u);
    }
    if (prob == 0 && blockIdx.x == 0) {
      // Dx diag (fp-noisy): weight -1 each (mod-2^32 exact)
      for (int i = threadIdx.x; i < Md; i += 256)
        histo(Mptr[(size_t)i * Md + i], 0xFFFFFFFFu);
    }
    if (prob == 1 && blockIdx.x == 0 && threadIdx.x == 0) {
      // Dy diag is exactly 0.0: subtract m at key(0.0)
      histo(0.0f, (unsigned)(-(int)Md));
    }
  } else {
    // components: triangle, paired rows (ra, 2047-ra) -> 2049 elems/pair,
    // 4 pairs/block (NB=256 -> ra covers 0..1023, rb covers 2047..1024).
    #pragma unroll 1
    for (int p = 0; p < 4; ++p) {
      int ra = blockIdx.x * 4 + p;      // 0..1023
      int rb = 2047 - ra;               // 2047..1024
      float ya = ycol[ra], yb = ycol[rb];
      int lena = ra + 1;                // row ra: j in [0, ra]
      for (int t = threadIdx.x; t < 2049; t += 256) {
        bool inA = (t < lena);
        int j = inA ? t : (t - lena);   // row rb: j in [0, rb]
        float yi = inA ? ya : yb;
        float d = yi - ycol[j];
        histo(d * d, 4u);
      }
    }
    // diag of each row is exactly 0.0 with weight 4 above; true weight 1:
    // subtract 3m at key(0.0) once per problem.
    if (blockIdx.x == 0 && threadIdx.x == 0)
      histo(0.0f, (unsigned)(-3 * (int)Md));
  }
  __syncthreads();
  unsigned* ghA = histA + prob * NBINS;
  for (int b = threadIdx.x; b < nbins; b += 256) {
    unsigned v = lh[b];
    if (v) atomicAdd(&ghA[b], v);
  }
}

// dual-rank select (grid 12, tiny): lo from histA; hi from histA while
// converged, histB after. At level 2 also computes q (2*sigma^2) directly.
__global__ __launch_bounds__(256) void select_kernel(unsigned* __restrict__ histA,
                                                     unsigned* __restrict__ histB,
                                                     unsigned* __restrict__ jobs,
                                                     float* __restrict__ q,
                                                     int level) {
  __shared__ unsigned lhA[NBINS], lhB[NBINS];
  __shared__ unsigned psA[256], psB[256];
  int prob = blockIdx.x;
  int nbins = (level == 2) ? 256 : NBINS;
  int C = (nbins + 255) / 256;     // 16 or 1
  unsigned* ghA = histA + prob * NBINS;
  unsigned* ghB = histB + prob * NBINS;
  unsigned sA = 0, sB = 0;
  for (int k = 0; k < C; ++k) {
    int b = threadIdx.x * C + k;
    if (b < nbins) {
      unsigned v = ghA[b]; lhA[b] = v; sA += v;
      unsigned u = ghB[b]; lhB[b] = u; sB += u;
    }
  }
  psA[threadIdx.x] = sA; psB[threadIdx.x] = sB;
  __syncthreads();
  if (threadIdx.x == 0) {
    unsigned pfxL = jobs[prob * 5 + 0], remL = jobs[prob * 5 + 1];
    unsigned pfxH = jobs[prob * 5 + 2], remH = jobs[prob * 5 + 3];
    unsigned wasdiv = jobs[prob * 5 + 4];

    auto scan = [&](const unsigned* ps, const unsigned* lhp, unsigned r,
                    int& bin, unsigned& cum) {
      unsigned c = 0; int t = 0;
      for (; t < 255; ++t) { if (c + ps[t] > r) break; c += ps[t]; }
      int b = t * C;
      int be = b + C - 1; if (be > nbins - 1) be = nbins - 1;
      for (; b < be; ++b) { if (c + lhp[b] > r) break; c += lhp[b]; }
      bin = b; cum = c;
    };

    int bL; unsigned cL; scan(psA, lhA, remL, bL, cL);
    int bH; unsigned cH;
    unsigned div = wasdiv;
    if (!wasdiv) {
      scan(psA, lhA, remH, bH, cH);
      if (bH != bL) div = 1;
    } else {
      scan(psB, lhB, remH, bH, cH);
    }
    unsigned baseH = wasdiv ? pfxH : pfxL;
    if (level < 2) {
      jobs[prob * 5 + 0] = (level == 0) ? (unsigned)bL : ((pfxL << 12) | (unsigned)bL);
      jobs[prob * 5 + 2] = (level == 0) ? (unsigned)bH : ((baseH << 12) | (unsigned)bH);
      jobs[prob * 5 + 1] = remL - cL;
      jobs[prob * 5 + 3] = remH - cH;
      jobs[prob * 5 + 4] = div;
    } else {
      unsigned keyL = (pfxL << 8) | (unsigned)bL;
      unsigned keyH = (baseH << 8) | (unsigned)bH;
      float med = 0.5f * (keyinv(keyL) + keyinv(keyH));
      med = fmaxf(med, 0.01f);
      q[prob] = 2.0f * med * med;   // 2*sigma^2
    }
  }
  __syncthreads();
  for (int b = threadIdx.x; b < nbins; b += 256) { ghA[b] = 0; ghB[b] = 0; }
}

// phase3a: rowgrand (blocks 0..255) + comp_rowsum (256..767). Both low-VGPR;
// comp_grand is SEPARATE (55 fp32 accs need their own allocation — merged
// it spilled 49 MB to scratch, R9 post-mortem).
__global__ __launch_bounds__(256) void phase3a_kernel(const float* __restrict__ Dx,
                                                      const float* __restrict__ Dy,
                                                      const float* __restrict__ Yt,
                                                      const float* __restrict__ q,
                                                      double* __restrict__ Rx,
                                                      double* __restrict__ Ry,
                                                      double* __restrict__ Rc,
                                                      double* __restrict__ gacc) {
  __shared__ double shred[12];
  const int wave = threadIdx.x >> 6, lane = threadIdx.x & 63;
  int bb = blockIdx.x;

  if (bb < 256) {
    // ---- rowgrand: Rx/Ry row sums + Gxx/Gxy/Gyy. expm1f REQUIRED here:
    // Dx's e ~ -3e-4 and centered values ~1e-5 need full relative precision.
    const float qx = q[0], qy = q[1];
    double gxx = 0, gxy = 0, gyy = 0;
    #pragma unroll
    for (int rr = 0; rr < 2; ++rr) {
      int i = bb * 4 + wave + rr * 1024;
      const float4* rx4 = (const float4*)(Dx + (size_t)i * Md);
      const float4* ry4 = (const float4*)(Dy + (size_t)i * Md);
      double ax = 0, ay = 0;
      #pragma unroll
      for (int it = 0; it < 8; ++it) {
        float4 xv = rx4[it * 64 + lane];
        float4 yv = ry4[it * 64 + lane];
        #pragma unroll
        for (int u = 0; u < 4; ++u) {
          float xe = (u == 0) ? xv.x : (u == 1) ? xv.y : (u == 2) ? xv.z : xv.w;
          float ye = (u == 0) ? yv.x : (u == 1) ? yv.y : (u == 2) ? yv.z : yv.w;
          float ex = expm1f(-(xe / qx));
          float ey = expm1f(-(ye / qy));
          ax += (double)ex; ay += (double)ey;
          gxx += (double)ex * ex;
          gxy += (double)ex * ey;
          gyy += (double)ey * ey;
        }
      }
      ax = waveReduceD(ax);
      ay = waveReduceD(ay);
      if (lane == 0) { Rx[i] = ax; Ry[i] = ay; }
    }
    gxx = waveReduceD(gxx);
    gxy = waveReduceD(gxy);
    gyy = waveReduceD(gyy);
    if (lane == 0) { shred[wave] = gxx; shred[4 + wave] = gxy; shred[8 + wave] = gyy; }
    __syncthreads();
    if (threadIdx.x == 0) {
      atomicAdd(&gacc[0], shred[0] + shred[1] + shred[2] + shred[3]);
      atomicAdd(&gacc[1], shred[4] + shred[5] + shred[6] + shred[7]);
      atomicAdd(&gacc[2], shred[8] + shred[9] + shred[10] + shred[11]);
    }
  } else {
    // ---- comp_rowsum: wave-per-row, coalesced float4 from Yt, fast __expf
    // (components have e ~ O(0.3); 6e-8 abs exp error is ~1e-7-relative).
    int i = (bb - 256) * 4 + wave;
    float yi[10], ninv[10];
    #pragma unroll
    for (int c = 0; c < 10; ++c) { yi[c] = Yt[c * Md + i]; ninv[c] = -1.0f / q[2 + c]; }
    float facc[10] = {};
    #pragma unroll 2
    for (int it = 0; it < 8; ++it) {
      int j = it * 256 + lane * 4;
      #pragma unroll
      for (int c = 0; c < 10; ++c) {
        float4 v = *(const float4*)(Yt + c * Md + j);
        float d0 = yi[c] - v.x, d1 = yi[c] - v.y, d2 = yi[c] - v.z, d3 = yi[c] - v.w;
        facc[c] += __expf(d0 * d0 * ninv[c]) - 1.0f;
        facc[c] += __expf(d1 * d1 * ninv[c]) - 1.0f;
        facc[c] += __expf(d2 * d2 * ninv[c]) - 1.0f;
        facc[c] += __expf(d3 * d3 * ninv[c]) - 1.0f;
      }
    }
    #pragma unroll
    for (int c = 0; c < 10; ++c) {
      double r = waveReduceD((double)facc[c]);
      if (lane == 0) Rc[c * Md + i] = r;
    }
  }
}

// comp_grand: Gc[a<=b] = sum_ij E_a*E_b = 2 * sum over tournament pairs
// (j, (j+d) mod m), d=1..m/2 (d=m/2 only for j<m/2; diag contributes 0 since
// e(i,i)=exp(0)-1=0). Halves exp+FMA work vs full matrix; i=(j+d)&2047 loads
// are coalesced. Grid 1024 blocks (4 waves/SIMD; R13: 512 was latency-bound
// at 2/SIMD). Thread owns column j; 8 d's per thread.
__global__ __launch_bounds__(256) void comp_grand_kernel(const float* __restrict__ Yt,
                                                         const float* __restrict__ q,
                                                         double* __restrict__ gacc) {
  __shared__ double shred[220];
  const int wave = threadIdx.x >> 6, lane = threadIdx.x & 63;
  float ninv[10];
  #pragma unroll
  for (int c = 0; c < 10; ++c) ninv[c] = -1.0f / q[2 + c];
  int tid0 = blockIdx.x * 256 + threadIdx.x;   // 1024*256 = 262144 threads
  int j = tid0 & 2047;
  int dg = tid0 >> 11;                         // 0..127 -> d in [dg*8+1, dg*8+8]
  float yj[10];
  #pragma unroll
  for (int c = 0; c < 10; ++c) yj[c] = Yt[c * Md + j];
  float facc[55];
  #pragma unroll
  for (int k = 0; k < 55; ++k) facc[k] = 0.0f;
  #pragma unroll 1
  for (int u = 1; u <= 8; ++u) {
    int d = dg * 8 + u;                        // 1..1024
    if (d == 1024 && j >= 1024) break;         // d=m/2 pairs counted once
    int i = (j + d) & 2047;
    float e[10];
    #pragma unroll
    for (int c = 0; c < 10; ++c) {
      float dd = Yt[c * Md + i] - yj[c];
      e[c] = __expf(dd * dd * ninv[c]) - 1.0f;
    }
    int k = 0;
    #pragma unroll
    for (int a = 0; a < 10; ++a)
      #pragma unroll
      for (int b = a; b < 10; ++b) { facc[k] = fmaf(e[a], e[b], facc[k]); ++k; }
  }
  #pragma unroll
  for (int k = 0; k < 55; ++k) {
    double v = waveReduceD((double)facc[k]);
    if (lane == 0) shred[k * 4 + wave] = v;
  }
  __syncthreads();
  for (int k = threadIdx.x; k < 55; k += 256) {
    double v = shred[k * 4] + shred[k * 4 + 1] + shred[k * 4 + 2] + shred[k * 4 + 3];
    atomicAdd(&gacc[3 + k], 2.0 * v);          // unordered pairs x2
  }
}

// 70 independent reductions, one block each (no per-thread arrays -> no spill).
// res[0..4]=sA,sB,sAB,sAA,sBB ; [5..14]=tr[c] ; [15..69]=rr[a<=b]
__global__ __launch_bounds__(256) void final_sums_kernel(const double* __restrict__ Rx,
                                                         const double* __restrict__ Ry,
                                                         const double* __restrict__ Rc,
                                                         double* __restrict__ res) {
  int k = blockIdx.x;
  double acc = 0.0;
  if (k < 5) {
    for (int i = threadIdx.x; i < Md; i += 256) {
      double a = Rx[i], b = Ry[i];
      acc += (k == 0) ? a : (k == 1) ? b : (k == 2) ? a * b : (k == 3) ? a * a : b * b;
    }
  } else if (k < 15) {
    const double* p = Rc + (size_t)(k - 5) * Md;
    for (int i = threadIdx.x; i < Md; i += 256) acc += p[i];
  } else {
    int kk = k - 15;
    int a = 0;
    while (kk >= 10 - a) { kk -= 10 - a; ++a; }
    int b = a + kk;
    const double* pa = Rc + (size_t)a * Md;
    const double* pb = Rc + (size_t)b * Md;
    for (int i = threadIdx.x; i < Md; i += 256) acc += pa[i] * pb[i];
  }
  double r = blockReduceD(acc);
  if (threadIdx.x == 0) res[k] = r;
}

// tiny scalar epilogue
__global__ void final_combine_kernel(const double* __restrict__ res,
                                     const double* __restrict__ gacc,
                                     float* __restrict__ out) {
  if (threadIdx.x != 0) return;
  const double m = (double)Md, m2 = m * m;
  double Gxx = gacc[0], Gxy = gacc[1], Gyy = gacc[2];
  double Sxy = Gxy - (2.0 / m) * res[2] + (res[0] * res[1]) / m2;
  double Sxx = Gxx - (2.0 / m) * res[3] + (res[0] * res[0]) / m2;
  double Syy = Gyy - (2.0 / m) * res[4] + (res[1] * res[1]) / m2;
  double mi_io = Sxy / sqrt(Sxx * Syy);

  double Sc[55], diag[10];
  int k = 0;
  for (int a = 0; a < 10; ++a)
    for (int b = a; b < 10; ++b) {
      double S = gacc[3 + k] - (2.0 / m) * res[15 + k] + (res[5 + a] * res[5 + b]) / m2;
      Sc[k] = S;
      if (a == b) diag[a] = S;
      ++k;
    }
  double comp = 0.0;
  k = 0;
  for (int a = 0; a < 10; ++a)
    for (int b = a; b < 10; ++b) {
      if (b > a) comp += Sc[k] / sqrt(diag[a] * diag[b]);
      ++k;
    }
  out[0] = (float)(-mi_io + comp);
}

// ---------------- launch ----------------
extern "C" void kernel_launch(void* const* d_in, const int* in_sizes, int n_in,
                              void* d_out, int out_size, void* d_ws, size_t ws_size,
                              hipStream_t stream) {
  const float* X = (const float*)d_in[0];
  const float* Y = (const float*)d_in[1];
  float* out = (float*)d_out;
  char* ws = (char*)d_ws;

  if (ws_size < WS_NEED) {
    fail_kernel<<<1, 64, 0, stream>>>(out);
    return;
  }

  float*    Dx    = (float*)(ws + OFF_DX);
  float*    Dy    = (float*)(ws + OFF_DY);
  double*   Rx    = (double*)(ws + OFF_RX);
  double*   Ry    = (double*)(ws + OFF_RY);
  double*   Rc    = (double*)(ws + OFF_RC);
  double*   gacc  = (double*)(ws + OFF_GACC);
  unsigned* histA = (unsigned*)(ws + OFF_HISTA);
  unsigned* histB = (unsigned*)(ws + OFF_HISTB);
  double*   res   = (double*)(ws + OFF_RES);
  unsigned* jobs  = (unsigned*)(ws + OFF_JOBS);
  float*    q     = (float*)(ws + OFF_Q);
  float*    rxn   = (float*)(ws + OFF_RXN);
  float*    Yt    = (float*)(ws + OFF_YT);

  hipMemsetAsync(ws + ZERO_BASE, 0, ZERO_LEN, stream);
  prep_kernel<<<Md + 80 + 1, 256, 0, stream>>>(X, Y, rxn, Yt, jobs);
  dist_kernel<<<dim3(NTRI, 1, 2), 256, 0, stream>>>(X, Y, rxn, Dx, Dy);

  for (int lvl = 0; lvl < 3; ++lvl) {
    hist_kernel<<<dim3(NB, NPROB), 256, 0, stream>>>(Dx, Dy, Yt, histA, histB, jobs, lvl);
    select_kernel<<<NPROB, 256, 0, stream>>>(histA, histB, jobs, q, lvl);
  }

  phase3a_kernel<<<768, 256, 0, stream>>>(Dx, Dy, Yt, q, Rx, Ry, Rc, gacc);
  comp_grand_kernel<<<1024, 256, 0, stream>>>(Yt, q, gacc);
  final_sums_kernel<<<70, 256, 0, stream>>>(Rx, Ry, Rc, res);
  final_combine_kernel<<<1, 64, 0, stream>>>(res, gacc, out);
}

// Round 15
// 379.360 us; speedup vs baseline: 1.0391x; 1.0391x over previous
//
#include <hip/hip_runtime.h>
#include <math.h>

// ---------------- problem constants (fixed by setup_inputs) ----------------
constexpr int Md   = 2048;      // m
constexpr int NDIM = 784;       // x feature dim
constexpr int DYC  = 10;        // y feature dim
constexpr int MM   = Md * Md;   // 4,194,304
// weighted median: per unordered pair i<j weight 4; diagonal weight 1.
// Dx/Dy: FULL matrix weight 2 (mirror bitwise equal) minus 1 per diag elem.
// Components: TRIANGLE weight 4 minus 3m at key(0.0) (diag exactly 0).
// Total each = 2m^2 - m = 8,386,560 (even).
constexpr unsigned RANK_LO = 4193279u;
constexpr unsigned RANK_HI = 4193280u;
constexpr int NPROB = 12;       // Dx, Dy, 10 components
constexpr int NB    = 256;      // blocks per problem
// Radix split 12/12/8 (R12 post-mortem: 13-bit lh = 40KB LDS capped occupancy
// at 4 blocks/CU on a latency-bound scan; 12-bit lh = 24KB -> 6 blocks/CU).
constexpr int NBINS = 4096;

// ---------------- workspace layout (bytes) ----------------
constexpr size_t OFF_DX     = 0;                          // float[MM]  16 MB
constexpr size_t OFF_DY     = OFF_DX + (size_t)MM * 4;    // float[MM]  16 MB
constexpr size_t OFF_RX     = OFF_DY + (size_t)MM * 4;    // double[2048]
constexpr size_t OFF_RY     = OFF_RX + Md * 8;            // double[2048]
constexpr size_t OFF_RC     = OFF_RY + Md * 8;            // double[10*2048]
constexpr size_t OFF_GACC   = OFF_RC + (size_t)DYC * Md * 8;   // double[64]
constexpr size_t OFF_HISTA  = OFF_GACC + 64 * 8;          // uint32[12*4096]
constexpr size_t OFF_HISTB  = OFF_HISTA + (size_t)NPROB * NBINS * 4;
constexpr size_t OFF_RES    = OFF_HISTB + (size_t)NPROB * NBINS * 4; // double[72]
constexpr size_t OFF_JOBS   = OFF_RES + 72 * 8;           // uint32[12*5]
constexpr size_t OFF_Q      = OFF_JOBS + NPROB * 5 * 4;   // float[12]: 2*sigma^2
constexpr size_t OFF_RXN    = OFF_Q + NPROB * 4;          // float[2048]
constexpr size_t OFF_YT     = OFF_RXN + Md * 4;           // float[10*2048]
constexpr size_t WS_NEED    = OFF_YT + (size_t)DYC * Md * 4;
constexpr size_t ZERO_BASE  = OFF_GACC;
constexpr size_t ZERO_LEN   = OFF_JOBS - OFF_GACC;        // gacc+histA+histB+res
constexpr int NTRI  = 528;      // 32*33/2 lower-triangle 64x64 block pairs

// ---------------- helpers ----------------
typedef _Float16 f16x8 __attribute__((ext_vector_type(8)));
typedef _Float16 f16x4 __attribute__((ext_vector_type(4)));
typedef float    f32x16 __attribute__((ext_vector_type(16)));

__device__ __forceinline__ unsigned fkey(float v) {
  unsigned u = __float_as_uint(v);
  return (u & 0x80000000u) ? ~u : (u | 0x80000000u);
}
__device__ __forceinline__ float keyinv(unsigned k) {
  unsigned u = (k & 0x80000000u) ? (k ^ 0x80000000u) : ~k;
  return __uint_as_float(u);
}
__device__ __forceinline__ f16x8 ld8(const _Float16* p) {
  f16x4 lo = *(const f16x4*)p;
  f16x4 hi = *(const f16x4*)(p + 4);
  f16x8 r;
  r[0]=lo[0]; r[1]=lo[1]; r[2]=lo[2]; r[3]=lo[3];
  r[4]=hi[0]; r[5]=hi[1]; r[6]=hi[2]; r[7]=hi[3];
  return r;
}
__device__ __forceinline__ double waveReduceD(double v) {
  #pragma unroll
  for (int o = 32; o > 0; o >>= 1) v += __shfl_down(v, o, 64);
  return v;
}
__device__ __forceinline__ float waveReduceF(float v) {
  #pragma unroll
  for (int o = 32; o > 0; o >>= 1) v += __shfl_down(v, o, 64);
  return v;
}
__device__ __forceinline__ double blockReduceD(double v) {
  __shared__ double sred[4];
  v = waveReduceD(v);
  int lane = threadIdx.x & 63;
  int w    = threadIdx.x >> 6;
  __syncthreads();
  if (lane == 0) sred[w] = v;
  __syncthreads();
  double r = 0.0;
  if (threadIdx.x == 0) { r = sred[0] + sred[1] + sred[2] + sred[3]; }
  return r;
}

// ---------------- kernels ----------------
__global__ void fail_kernel(float* out) { if (threadIdx.x == 0) out[0] = 0.0f; }

// prep: rownorm (blocks 0..2047) + Y transpose (2048..2127) + jobs init (2128)
__global__ __launch_bounds__(256) void prep_kernel(const float* __restrict__ X,
                                                   const float* __restrict__ Y,
                                                   float* __restrict__ rxn,
                                                   float* __restrict__ Yt,
                                                   unsigned* __restrict__ jobs) {
  int bb = blockIdx.x;
  if (bb < Md) {
    double acc = 0.0;
    for (int k = threadIdx.x; k < NDIM; k += 256) {
      float v = X[bb * NDIM + k];
      acc += (double)v * (double)v;
    }
    double r = blockReduceD(acc);
    if (threadIdx.x == 0) rxn[bb] = (float)r;
  } else if (bb < Md + 80) {
    int e = (bb - Md) * 256 + threadIdx.x;
    if (e < Md * DYC) {
      int i = e / DYC, c = e % DYC;
      Yt[c * Md + i] = Y[e];
    }
  } else {
    int t = threadIdx.x;
    if (t < NPROB * 5) {
      int w = t % 5;
      jobs[t] = (w == 1) ? RANK_LO : (w == 3) ? RANK_HI : 0u;
    }
  }
}

// merged distance kernel over LOWER-TRIANGLE block pairs only (D symmetric;
// mirror-write both tiles — same value bitwise, fp add commutes).
// z=0: Dx via fp16 hi/lo split MFMA; z=1: Dy direct.
__global__ __launch_bounds__(256) void dist_kernel(const float* __restrict__ X,
                                                   const float* __restrict__ Y,
                                                   const float* __restrict__ rxn,
                                                   float* __restrict__ Dx,
                                                   float* __restrict__ Dy) {
  __shared__ _Float16 Ah[64][68], Al[64][68], Bh[64][68], Bl[64][68];
  __shared__ float Yi[64][10], Yj[64][10];
  const int tid = threadIdx.x;
  // map linear triangle index -> (bi, bj), bi >= bj
  int t0 = blockIdx.x;
  int bi = (int)((sqrtf(8.0f * (float)t0 + 1.0f) - 1.0f) * 0.5f);
  while ((bi + 1) * (bi + 2) / 2 <= t0) ++bi;
  while (bi * (bi + 1) / 2 > t0) --bi;
  int bj = t0 - bi * (bi + 1) / 2;
  const int i0 = bi * 64, j0 = bj * 64;
  const bool offdiag = (bi != bj);

  if (blockIdx.z == 1) {
    // ---- Dy[i,j] = sum_c (y_ic - y_jc)^2 ----
    for (int t = tid; t < 640; t += 256) {
      int r = t / 10, c = t % 10;
      Yi[r][c] = Y[(i0 + r) * DYC + c];
      Yj[r][c] = Y[(j0 + r) * DYC + c];
    }
    __syncthreads();
    int jj = tid & 63;
    int ii0 = (tid >> 6) * 16;
    float yj[10];
    #pragma unroll
    for (int c = 0; c < 10; ++c) yj[c] = Yj[jj][c];
    for (int r = 0; r < 16; ++r) {
      int ii = ii0 + r;
      float s = 0.f;
      #pragma unroll
      for (int c = 0; c < 10; ++c) { float d = Yi[ii][c] - yj[c]; s = fmaf(d, d, s); }
      Dy[(size_t)(i0 + ii) * Md + (j0 + jj)] = s;
      if (offdiag) Dy[(size_t)(j0 + jj) * Md + (i0 + ii)] = s;
    }
    return;
  }

  // ---- Dx = rx[i] + rx[j] - 2*(hh + (c1+c2)), fp16 hi/lo split MFMA ----
  const int wave = tid >> 6, lane = tid & 63;
  const int wr = (wave >> 1) * 32, wc = (wave & 1) * 32;
  const int srow = tid >> 2;
  const int sseg = (tid & 3) * 8;

  f32x16 acc_hh = {}, acc_c1 = {}, acc_c2 = {};

  const float* Arow = X + (size_t)(i0 + srow) * NDIM;
  const float* Brow = X + (size_t)(j0 + srow) * NDIM;
  const int lrow = lane & 31;
  const int lko  = (lane >> 5) * 8;

  for (int k0 = 0; k0 < 800; k0 += 32) {
    float a[8], b[8];
    if (k0 + 32 <= NDIM) {
      float4 a4 = *(const float4*)(Arow + k0 + sseg);
      float4 a5 = *(const float4*)(Arow + k0 + sseg + 4);
      float4 b4 = *(const float4*)(Brow + k0 + sseg);
      float4 b5 = *(const float4*)(Brow + k0 + sseg + 4);
      a[0]=a4.x; a[1]=a4.y; a[2]=a4.z; a[3]=a4.w; a[4]=a5.x; a[5]=a5.y; a[6]=a5.z; a[7]=a5.w;
      b[0]=b4.x; b[1]=b4.y; b[2]=b4.z; b[3]=b4.w; b[4]=b5.x; b[5]=b5.y; b[6]=b5.z; b[7]=b5.w;
    } else {
      #pragma unroll
      for (int u = 0; u < 8; ++u) {
        int k = k0 + sseg + u;
        a[u] = (k < NDIM) ? Arow[k] : 0.0f;
        b[u] = (k < NDIM) ? Brow[k] : 0.0f;
      }
    }
    __syncthreads();
    #pragma unroll
    for (int half = 0; half < 2; ++half) {
      f16x4 vah, val_, vbh, vbl;
      #pragma unroll
      for (int u = 0; u < 4; ++u) {
        float av = a[half * 4 + u];
        _Float16 h = (_Float16)av;
        vah[u] = h; val_[u] = (_Float16)(av - (float)h);
        float bv = b[half * 4 + u];
        _Float16 g = (_Float16)bv;
        vbh[u] = g; vbl[u] = (_Float16)(bv - (float)g);
      }
      *(f16x4*)&Ah[srow][sseg + half * 4] = vah;
      *(f16x4*)&Al[srow][sseg + half * 4] = val_;
      *(f16x4*)&Bh[srow][sseg + half * 4] = vbh;
      *(f16x4*)&Bl[srow][sseg + half * 4] = vbl;
    }
    __syncthreads();
    #pragma unroll
    for (int ks = 0; ks < 2; ++ks) {
      int ko = ks * 16 + lko;
      f16x8 fah = ld8(&Ah[wr + lrow][ko]);
      f16x8 fal = ld8(&Al[wr + lrow][ko]);
      f16x8 fbh = ld8(&Bh[wc + lrow][ko]);
      f16x8 fbl = ld8(&Bl[wc + lrow][ko]);
      acc_hh = __builtin_amdgcn_mfma_f32_32x32x16_f16(fah, fbh, acc_hh, 0, 0, 0);
      acc_c1 = __builtin_amdgcn_mfma_f32_32x32x16_f16(fah, fbl, acc_c1, 0, 0, 0);
      acc_c2 = __builtin_amdgcn_mfma_f32_32x32x16_f16(fal, fbh, acc_c2, 0, 0, 0);
    }
  }
  int col = j0 + wc + (lane & 31);
  float rj = rxn[col];
  #pragma unroll
  for (int r = 0; r < 16; ++r) {
    int row = i0 + wr + (r & 3) + 8 * (r >> 2) + 4 * (lane >> 5);
    float t = rxn[row] + rj;
    float cc = acc_c1[r] + acc_c2[r];
    float v = fmaf(-2.0f, cc, fmaf(-2.0f, acc_hh[r], t));
    Dx[(size_t)row * Md + col] = v;
    if (offdiag) Dx[(size_t)col * Md + row] = v;   // mirror (bitwise-equal value)
  }
}

// radix-select histogram, split 12/12/8. Dx/Dy (probs 0,1): FULL-matrix flat
// float4 scan, weight 2, minus diag (Dx: per-elem -1 rescan; Dy: -m at
// key(0)). Components (probs 2-11, LDS-computed): TRIANGLE with paired rows
// (ra, 2047-ra) -> uniform 2049 elems/pair, weight 4, minus 3m at key(0.0).
// 24KB LDS -> 6 blocks/CU (the scan is latency-bound; occupancy is the fix).
// grid (NB, 12). Levels: 12 bits [31:20], 12 bits [19:8], 8 bits [7:0].
__global__ __launch_bounds__(256) void hist_kernel(const float* __restrict__ Dx,
                                                   const float* __restrict__ Dy,
                                                   const float* __restrict__ Yt,
                                                   unsigned* __restrict__ histA,
                                                   unsigned* __restrict__ histB,
                                                   const unsigned* __restrict__ jobs,
                                                   int level) {
  __shared__ unsigned lh[NBINS];   // 16 KB
  __shared__ float ycol[Md];       // 8 KB
  int prob = blockIdx.y;
  int nbins = (level == 2) ? 256 : NBINS;
  for (int b = threadIdx.x; b < nbins; b += 256) lh[b] = 0;
  const float* Mptr = (prob == 0) ? Dx : (prob == 1 ? Dy : nullptr);
  if (prob >= 2) {
    const float* src = Yt + (size_t)(prob - 2) * Md;
    for (int i = threadIdx.x; i < Md; i += 256) ycol[i] = src[i];
  }
  __syncthreads();
  unsigned pfxL = jobs[prob * 5 + 0];
  unsigned pfxH = jobs[prob * 5 + 2];
  unsigned div  = jobs[prob * 5 + 4];
  unsigned* ghB = histB + prob * NBINS;

  auto histo = [&](float v, unsigned w) {
    unsigned key = fkey(v);
    if (level == 0) {
      atomicAdd(&lh[key >> 20], w);
    } else if (level == 1) {
      if ((key >> 20) == pfxL)             atomicAdd(&lh[(key >> 8) & 4095u], w);
      else if (div && (key >> 20) == pfxH) atomicAdd(&ghB[(key >> 8) & 4095u], w);
    } else {
      if ((key >> 8) == pfxL)              atomicAdd(&lh[key & 255u], w);
      else if (div && (key >> 8) == pfxH)  atomicAdd(&ghB[key & 255u], w);
    }
  };

  if (Mptr) {
    // flat chunk: 16384 elements = 4096 float4 per block
    const float4* M4 = (const float4*)Mptr + (size_t)blockIdx.x * 4096;
    #pragma unroll 1
    for (int it = 0; it < 16; it += 4) {
      float4 v0 = M4[(it + 0) * 256 + threadIdx.x];
      float4 v1 = M4[(it + 1) * 256 + threadIdx.x];
      float4 v2 = M4[(it + 2) * 256 + threadIdx.x];
      float4 v3 = M4[(it + 3) * 256 + threadIdx.x];
      histo(v0.x, 2u); histo(v0.y, 2u); histo(v0.z, 2u); histo(v0.w, 2u);
      histo(v1.x, 2u); histo(v1.y, 2u); histo(v1.z, 2u); histo(v1.w, 2u);
      histo(v2.x, 2u); histo(v2.y, 2u); histo(v2.z, 2u); histo(v2.w, 2u);
      histo(v3.x, 2u); histo(v3.y, 2u); histo(v3.z, 2u); histo(v3.w, 2u);
    }
    if (prob == 0 && blockIdx.x == 0) {
      // Dx diag (fp-noisy): weight -1 each (mod-2^32 exact)
      for (int i = threadIdx.x; i < Md; i += 256)
        histo(Mptr[(size_t)i * Md + i], 0xFFFFFFFFu);
    }
    if (prob == 1 && blockIdx.x == 0 && threadIdx.x == 0) {
      // Dy diag is exactly 0.0: subtract m at key(0.0)
      histo(0.0f, (unsigned)(-(int)Md));
    }
  } else {
    // components: triangle, paired rows (ra, 2047-ra) -> 2049 elems/pair,
    // 4 pairs/block (NB=256 -> ra covers 0..1023, rb covers 2047..1024).
    #pragma unroll 1
    for (int p = 0; p < 4; ++p) {
      int ra = blockIdx.x * 4 + p;      // 0..1023
      int rb = 2047 - ra;               // 2047..1024
      float ya = ycol[ra], yb = ycol[rb];
      int lena = ra + 1;                // row ra: j in [0, ra]
      for (int t = threadIdx.x; t < 2049; t += 256) {
        bool inA = (t < lena);
        int j = inA ? t : (t - lena);   // row rb: j in [0, rb]
        float yi = inA ? ya : yb;
        float d = yi - ycol[j];
        histo(d * d, 4u);
      }
    }
    // diag of each row is exactly 0.0 with weight 4 above; true weight 1:
    // subtract 3m at key(0.0) once per problem.
    if (blockIdx.x == 0 && threadIdx.x == 0)
      histo(0.0f, (unsigned)(-3 * (int)Md));
  }
  __syncthreads();
  unsigned* ghA = histA + prob * NBINS;
  for (int b = threadIdx.x; b < nbins; b += 256) {
    unsigned v = lh[b];
    if (v) atomicAdd(&ghA[b], v);
  }
}

// dual-rank select (grid 12, tiny): lo from histA; hi from histA while
// converged, histB after. At level 2 also computes q (2*sigma^2) directly.
__global__ __launch_bounds__(256) void select_kernel(unsigned* __restrict__ histA,
                                                     unsigned* __restrict__ histB,
                                                     unsigned* __restrict__ jobs,
                                                     float* __restrict__ q,
                                                     int level) {
  __shared__ unsigned lhA[NBINS], lhB[NBINS];
  __shared__ unsigned psA[256], psB[256];
  int prob = blockIdx.x;
  int nbins = (level == 2) ? 256 : NBINS;
  int C = (nbins + 255) / 256;     // 16 or 1
  unsigned* ghA = histA + prob * NBINS;
  unsigned* ghB = histB + prob * NBINS;
  unsigned sA = 0, sB = 0;
  for (int k = 0; k < C; ++k) {
    int b = threadIdx.x * C + k;
    if (b < nbins) {
      unsigned v = ghA[b]; lhA[b] = v; sA += v;
      unsigned u = ghB[b]; lhB[b] = u; sB += u;
    }
  }
  psA[threadIdx.x] = sA; psB[threadIdx.x] = sB;
  __syncthreads();
  if (threadIdx.x == 0) {
    unsigned pfxL = jobs[prob * 5 + 0], remL = jobs[prob * 5 + 1];
    unsigned pfxH = jobs[prob * 5 + 2], remH = jobs[prob * 5 + 3];
    unsigned wasdiv = jobs[prob * 5 + 4];

    auto scan = [&](const unsigned* ps, const unsigned* lhp, unsigned r,
                    int& bin, unsigned& cum) {
      unsigned c = 0; int t = 0;
      for (; t < 255; ++t) { if (c + ps[t] > r) break; c += ps[t]; }
      int b = t * C;
      int be = b + C - 1; if (be > nbins - 1) be = nbins - 1;
      for (; b < be; ++b) { if (c + lhp[b] > r) break; c += lhp[b]; }
      bin = b; cum = c;
    };

    int bL; unsigned cL; scan(psA, lhA, remL, bL, cL);
    int bH; unsigned cH;
    unsigned div = wasdiv;
    if (!wasdiv) {
      scan(psA, lhA, remH, bH, cH);
      if (bH != bL) div = 1;
    } else {
      scan(psB, lhB, remH, bH, cH);
    }
    unsigned baseH = wasdiv ? pfxH : pfxL;
    if (level < 2) {
      jobs[prob * 5 + 0] = (level == 0) ? (unsigned)bL : ((pfxL << 12) | (unsigned)bL);
      jobs[prob * 5 + 2] = (level == 0) ? (unsigned)bH : ((baseH << 12) | (unsigned)bH);
      jobs[prob * 5 + 1] = remL - cL;
      jobs[prob * 5 + 3] = remH - cH;
      jobs[prob * 5 + 4] = div;
    } else {
      unsigned keyL = (pfxL << 8) | (unsigned)bL;
      unsigned keyH = (baseH << 8) | (unsigned)bH;
      float med = 0.5f * (keyinv(keyL) + keyinv(keyH));
      med = fmaxf(med, 0.01f);
      q[prob] = 2.0f * med * med;   // 2*sigma^2
    }
  }
  __syncthreads();
  for (int b = threadIdx.x; b < nbins; b += 256) { ghA[b] = 0; ghB[b] = 0; }
}

// phase3a: rowgrand (blocks 0..255) + comp_rowsum (256..767). Both low-VGPR;
// comp_grand is SEPARATE (55 fp32 accs need their own allocation — merged
// it spilled 49 MB to scratch, R9 post-mortem).
__global__ __launch_bounds__(256) void phase3a_kernel(const float* __restrict__ Dx,
                                                      const float* __restrict__ Dy,
                                                      const float* __restrict__ Yt,
                                                      const float* __restrict__ q,
                                                      double* __restrict__ Rx,
                                                      double* __restrict__ Ry,
                                                      double* __restrict__ Rc,
                                                      double* __restrict__ gacc) {
  __shared__ double shred[12];
  const int wave = threadIdx.x >> 6, lane = threadIdx.x & 63;
  int bb = blockIdx.x;

  if (bb < 256) {
    // ---- rowgrand: Rx/Ry row sums + Gxx/Gxy/Gyy. expm1f REQUIRED here:
    // Dx's e ~ -3e-4 and centered values ~1e-5 need full relative precision.
    const float qx = q[0], qy = q[1];
    double gxx = 0, gxy = 0, gyy = 0;
    #pragma unroll
    for (int rr = 0; rr < 2; ++rr) {
      int i = bb * 4 + wave + rr * 1024;
      const float4* rx4 = (const float4*)(Dx + (size_t)i * Md);
      const float4* ry4 = (const float4*)(Dy + (size_t)i * Md);
      double ax = 0, ay = 0;
      #pragma unroll
      for (int it = 0; it < 8; ++it) {
        float4 xv = rx4[it * 64 + lane];
        float4 yv = ry4[it * 64 + lane];
        #pragma unroll
        for (int u = 0; u < 4; ++u) {
          float xe = (u == 0) ? xv.x : (u == 1) ? xv.y : (u == 2) ? xv.z : xv.w;
          float ye = (u == 0) ? yv.x : (u == 1) ? yv.y : (u == 2) ? yv.z : yv.w;
          float ex = expm1f(-(xe / qx));
          float ey = expm1f(-(ye / qy));
          ax += (double)ex; ay += (double)ey;
          gxx += (double)ex * ex;
          gxy += (double)ex * ey;
          gyy += (double)ey * ey;
        }
      }
      ax = waveReduceD(ax);
      ay = waveReduceD(ay);
      if (lane == 0) { Rx[i] = ax; Ry[i] = ay; }
    }
    gxx = waveReduceD(gxx);
    gxy = waveReduceD(gxy);
    gyy = waveReduceD(gyy);
    if (lane == 0) { shred[wave] = gxx; shred[4 + wave] = gxy; shred[8 + wave] = gyy; }
    __syncthreads();
    if (threadIdx.x == 0) {
      atomicAdd(&gacc[0], shred[0] + shred[1] + shred[2] + shred[3]);
      atomicAdd(&gacc[1], shred[4] + shred[5] + shred[6] + shred[7]);
      atomicAdd(&gacc[2], shred[8] + shred[9] + shred[10] + shred[11]);
    }
  } else {
    // ---- comp_rowsum: wave-per-row, coalesced float4 from Yt, fast __expf
    // (components have e ~ O(0.3); 6e-8 abs exp error is ~1e-7-relative).
    int i = (bb - 256) * 4 + wave;
    float yi[10], ninv[10];
    #pragma unroll
    for (int c = 0; c < 10; ++c) { yi[c] = Yt[c * Md + i]; ninv[c] = -1.0f / q[2 + c]; }
    float facc[10] = {};
    #pragma unroll 2
    for (int it = 0; it < 8; ++it) {
      int j = it * 256 + lane * 4;
      #pragma unroll
      for (int c = 0; c < 10; ++c) {
        float4 v = *(const float4*)(Yt + c * Md + j);
        float d0 = yi[c] - v.x, d1 = yi[c] - v.y, d2 = yi[c] - v.z, d3 = yi[c] - v.w;
        facc[c] += __expf(d0 * d0 * ninv[c]) - 1.0f;
        facc[c] += __expf(d1 * d1 * ninv[c]) - 1.0f;
        facc[c] += __expf(d2 * d2 * ninv[c]) - 1.0f;
        facc[c] += __expf(d3 * d3 * ninv[c]) - 1.0f;
      }
    }
    #pragma unroll
    for (int c = 0; c < 10; ++c) {
      double r = waveReduceD((double)facc[c]);
      if (lane == 0) Rc[c * Md + i] = r;
    }
  }
}

// comp_grand: Gc[a<=b] = 2 * sum over tournament pairs (j, (j+d) mod m),
// d=1..m/2 (d=m/2 only for j<m/2; diag contributes 0). 512 blocks x 16 d's
// per thread. R14 post-mortem: the 55x fp64 shuffle tail cost ~7us/block
// (55 accs exceed arch VGPRs; 64-bit shuffles = 2x ds_bpermute with long
// dependent chains) — reduce cross-lane in FP32 (1 shuffle/step, chains fit
// in VGPRs; wave-tree error ~1e-8 relative on Gc), convert to fp64 at the
// 4-way LDS stage; halve block count to amortize what remains.
__global__ __launch_bounds__(256) void comp_grand_kernel(const float* __restrict__ Yt,
                                                         const float* __restrict__ q,
                                                         double* __restrict__ gacc) {
  __shared__ float shred[220];
  const int wave = threadIdx.x >> 6, lane = threadIdx.x & 63;
  float ninv[10];
  #pragma unroll
  for (int c = 0; c < 10; ++c) ninv[c] = -1.0f / q[2 + c];
  int tid0 = blockIdx.x * 256 + threadIdx.x;   // 512*256 = 131072 threads
  int j = tid0 & 2047;
  int dg = tid0 >> 11;                         // 0..63 -> d in [dg*16+1, dg*16+16]
  float yj[10];
  #pragma unroll
  for (int c = 0; c < 10; ++c) yj[c] = Yt[c * Md + j];
  float facc[55];
  #pragma unroll
  for (int k = 0; k < 55; ++k) facc[k] = 0.0f;
  #pragma unroll 1
  for (int u = 1; u <= 16; ++u) {
    int d = dg * 16 + u;                       // 1..1024
    if (d == 1024 && j >= 1024) break;         // d=m/2 pairs counted once
    int i = (j + d) & 2047;
    float e[10];
    #pragma unroll
    for (int c = 0; c < 10; ++c) {
      float dd = Yt[c * Md + i] - yj[c];
      e[c] = __expf(dd * dd * ninv[c]) - 1.0f;
    }
    int k = 0;
    #pragma unroll
    for (int a = 0; a < 10; ++a)
      #pragma unroll
      for (int b = a; b < 10; ++b) { facc[k] = fmaf(e[a], e[b], facc[k]); ++k; }
  }
  #pragma unroll
  for (int k = 0; k < 55; ++k) {
    float v = waveReduceF(facc[k]);            // fp32 shuffles: 1 op/step
    if (lane == 0) shred[k * 4 + wave] = v;
  }
  __syncthreads();
  for (int k = threadIdx.x; k < 55; k += 256) {
    double v = (double)shred[k * 4] + (double)shred[k * 4 + 1]
             + (double)shred[k * 4 + 2] + (double)shred[k * 4 + 3];
    atomicAdd(&gacc[3 + k], 2.0 * v);          // unordered pairs x2
  }
}

// 70 independent reductions, one block each (no per-thread arrays -> no spill).
// res[0..4]=sA,sB,sAB,sAA,sBB ; [5..14]=tr[c] ; [15..69]=rr[a<=b]
__global__ __launch_bounds__(256) void final_sums_kernel(const double* __restrict__ Rx,
                                                         const double* __restrict__ Ry,
                                                         const double* __restrict__ Rc,
                                                         double* __restrict__ res) {
  int k = blockIdx.x;
  double acc = 0.0;
  if (k < 5) {
    for (int i = threadIdx.x; i < Md; i += 256) {
      double a = Rx[i], b = Ry[i];
      acc += (k == 0) ? a : (k == 1) ? b : (k == 2) ? a * b : (k == 3) ? a * a : b * b;
    }
  } else if (k < 15) {
    const double* p = Rc + (size_t)(k - 5) * Md;
    for (int i = threadIdx.x; i < Md; i += 256) acc += p[i];
  } else {
    int kk = k - 15;
    int a = 0;
    while (kk >= 10 - a) { kk -= 10 - a; ++a; }
    int b = a + kk;
    const double* pa = Rc + (size_t)a * Md;
    const double* pb = Rc + (size_t)b * Md;
    for (int i = threadIdx.x; i < Md; i += 256) acc += pa[i] * pb[i];
  }
  double r = blockReduceD(acc);
  if (threadIdx.x == 0) res[k] = r;
}

// tiny scalar epilogue
__global__ void final_combine_kernel(const double* __restrict__ res,
                                     const double* __restrict__ gacc,
                                     float* __restrict__ out) {
  if (threadIdx.x != 0) return;
  const double m = (double)Md, m2 = m * m;
  double Gxx = gacc[0], Gxy = gacc[1], Gyy = gacc[2];
  double Sxy = Gxy - (2.0 / m) * res[2] + (res[0] * res[1]) / m2;
  double Sxx = Gxx - (2.0 / m) * res[3] + (res[0] * res[0]) / m2;
  double Syy = Gyy - (2.0 / m) * res[4] + (res[1] * res[1]) / m2;
  double mi_io = Sxy / sqrt(Sxx * Syy);

  double Sc[55], diag[10];
  int k = 0;
  for (int a = 0; a < 10; ++a)
    for (int b = a; b < 10; ++b) {
      double S = gacc[3 + k] - (2.0 / m) * res[15 + k] + (res[5 + a] * res[5 + b]) / m2;
      Sc[k] = S;
      if (a == b) diag[a] = S;
      ++k;
    }
  double comp = 0.0;
  k = 0;
  for (int a = 0; a < 10; ++a)
    for (int b = a; b < 10; ++b) {
      if (b > a) comp += Sc[k] / sqrt(diag[a] * diag[b]);
      ++k;
    }
  out[0] = (float)(-mi_io + comp);
}

// ---------------- launch ----------------
extern "C" void kernel_launch(void* const* d_in, const int* in_sizes, int n_in,
                              void* d_out, int out_size, void* d_ws, size_t ws_size,
                              hipStream_t stream) {
  const float* X = (const float*)d_in[0];
  const float* Y = (const float*)d_in[1];
  float* out = (float*)d_out;
  char* ws = (char*)d_ws;

  if (ws_size < WS_NEED) {
    fail_kernel<<<1, 64, 0, stream>>>(out);
    return;
  }

  float*    Dx    = (float*)(ws + OFF_DX);
  float*    Dy    = (float*)(ws + OFF_DY);
  double*   Rx    = (double*)(ws + OFF_RX);
  double*   Ry    = (double*)(ws + OFF_RY);
  double*   Rc    = (double*)(ws + OFF_RC);
  double*   gacc  = (double*)(ws + OFF_GACC);
  unsigned* histA = (unsigned*)(ws + OFF_HISTA);
  unsigned* histB = (unsigned*)(ws + OFF_HISTB);
  double*   res   = (double*)(ws + OFF_RES);
  unsigned* jobs  = (unsigned*)(ws + OFF_JOBS);
  float*    q     = (float*)(ws + OFF_Q);
  float*    rxn   = (float*)(ws + OFF_RXN);
  float*    Yt    = (float*)(ws + OFF_YT);

  hipMemsetAsync(ws + ZERO_BASE, 0, ZERO_LEN, stream);
  prep_kernel<<<Md + 80 + 1, 256, 0, stream>>>(X, Y, rxn, Yt, jobs);
  dist_kernel<<<dim3(NTRI, 1, 2), 256, 0, stream>>>(X, Y, rxn, Dx, Dy);

  for (int lvl = 0; lvl < 3; ++lvl) {
    hist_kernel<<<dim3(NB, NPROB), 256, 0, stream>>>(Dx, Dy, Yt, histA, histB, jobs, lvl);
    select_kernel<<<NPROB, 256, 0, stream>>>(histA, histB, jobs, q, lvl);
  }

  phase3a_kernel<<<768, 256, 0, stream>>>(Dx, Dy, Yt, q, Rx, Ry, Rc, gacc);
  comp_grand_kernel<<<512, 256, 0, stream>>>(Yt, q, gacc);
  final_sums_kernel<<<70, 256, 0, stream>>>(Rx, Ry, Rc, res);
  final_combine_kernel<<<1, 64, 0, stream>>>(res, gacc, out);
}